// Round 8
// baseline (265.593 us; speedup 1.0000x reference)
//
#include <hip/hip_runtime.h>
#include <hip/hip_bf16.h>
#include <hip/hip_cooperative_groups.h>
#include <cstdint>

namespace cg = cooperative_groups;

// out[M,N] = x[M,K] @ weight[N,K]^T, fp32 device buffers.
// Cooperative kernel, grid 256 x 512thr, 1 block/CU:
//  phase 1: cvt fp32->bf16 into d_ws, TILED+FRAGMENT-ORDERED layout
//  grid.sync()
//  phase 2: 256x256 GEMM, BK=64, 8 waves (2x4). Per K-step: single
//  vmcnt(2)+barrier publish of the whole compute set, then 4 MFMA clusters
//  with ds_reads of cluster p+1 overlapping cluster p's MFMA (no intra-step
//  barriers), B-frags held in registers across mh, counted vmcnt (never 0),
//  setprio around MFMA, end-of-step barrier. fp32 C.

typedef __bf16 bf16x8 __attribute__((ext_vector_type(8)));
typedef float f32x4 __attribute__((ext_vector_type(4)));
typedef unsigned short u16x8 __attribute__((ext_vector_type(8)));

#define GAS __attribute__((address_space(1)))
#define LAS __attribute__((address_space(3)))
#define ASYNC16(gsrc, ldst)                                                  \
    __builtin_amdgcn_global_load_lds((GAS uint32_t*)(const void*)(gsrc),     \
                                     (LAS uint32_t*)(ldst), 16, 0, 0)

__device__ inline unsigned short f2bf(float f) {
    __hip_bfloat16 h = __float2bfloat16(f);  // RNE
    return *reinterpret_cast<unsigned short*>(&h);
}

__global__ __launch_bounds__(512, 2) void coop_cvt_gemm3(
    const float* __restrict__ A32,       // x      [M,K]
    const float* __restrict__ B32,       // weight [N,K]
    unsigned short* __restrict__ ws,     // bf16 tiled [szX | szW]
    float* __restrict__ C,               // out    [M,N]
    int M, int N, int K)
{
    const int NT  = K >> 6;              // 64 K-steps
    const int szX = M * K;
    const int szW = N * K;

    // ================= phase 1: cvt fp32 -> tiled bf16 ws =================
    // chunk (16384 shorts) per (tile,kt); within: off = ks*8192 + g*2048 +
    // row*8 + e, where k = ks*32 + g*8.  (validated Round 7)
    {
        const int nA8 = szX >> 3;
        const int tot8 = (szX + szW) >> 3;
        const int S = gridDim.x * blockDim.x;
        for (int c = blockIdx.x * blockDim.x + threadIdx.x; c < tot8; c += S) {
            unsigned short* dst = ws + ((size_t)c << 3);
            int cl;
            const float* base;
            if (c < nA8) { cl = c;        base = A32; }
            else         { cl = c - nA8;  base = B32; }
            const int cid  = cl >> 11;
            const int c_in = cl & 2047;
            const int tile = cid >> 6;
            const int kt   = cid & 63;
            const int ks   = c_in >> 10;
            const int g    = (c_in >> 8) & 3;
            const int row  = c_in & 255;
            const float* src = base + (size_t)(tile * 256 + row) * K + kt * 64 + ks * 32 + g * 8;
            float4 v0 = *reinterpret_cast<const float4*>(src);
            float4 v1 = *reinterpret_cast<const float4*>(src + 4);
            u16x8 o;
            o[0] = f2bf(v0.x); o[1] = f2bf(v0.y); o[2] = f2bf(v0.z); o[3] = f2bf(v0.w);
            o[4] = f2bf(v1.x); o[5] = f2bf(v1.y); o[6] = f2bf(v1.z); o[7] = f2bf(v1.w);
            *reinterpret_cast<u16x8*>(dst) = o;
        }
    }

    cg::this_grid().sync();
    asm volatile("s_waitcnt vmcnt(0)" ::: "memory");  // clean vmcnt ledger

    // ================= phase 2: GEMM =================
    __shared__ unsigned short lds[2][2][16384];  // [set][A|B] = 128 KB

    const int nbm = M >> 8;              // 8
    const int nbn = N >> 8;              // 32
    const int bid = blockIdx.x;
    const int swzid = (bid & 7) * ((nbm * nbn) >> 3) + (bid >> 3);
    const int bm = swzid % nbm;          // fast: stream A panels
    const int bn = swzid / nbm;          // slow: B panel L2-resident

    const int tid  = threadIdx.x;
    const int wv   = tid >> 6;
    const int lane = tid & 63;
    const int wr   = wv >> 2;            // 0..1
    const int wc   = wv & 3;             // 0..3

    const unsigned short* wsA = ws + (size_t)(bm * NT) * 16384 + wv * 1024 + lane * 8;
    const unsigned short* wsB = ws + (size_t)szX + (size_t)(bn * NT) * 16384 + wv * 1024 + lane * 8;
    const int ldsWOff = wv * 1024;

    const int aBase = (lane >> 4) * 2048 + (wr * 128 + (lane & 15)) * 8;
    const int bBase = (lane >> 4) * 2048 + (wc * 64 + (lane & 15)) * 8;

    f32x4 acc[8][4] = {};

#define STAGE_A(half, tt, ss) do {                                            \
        const unsigned short* s_ = wsA + (size_t)(tt) * 16384 + (half) * 8192;\
        ASYNC16(s_,       &lds[ss][0][(half) * 8192 + ldsWOff]);              \
        ASYNC16(s_ + 512, &lds[ss][0][(half) * 8192 + ldsWOff + 512]);        \
    } while (0)
#define STAGE_B(half, tt, ss) do {                                            \
        const unsigned short* s_ = wsB + (size_t)(tt) * 16384 + (half) * 8192;\
        ASYNC16(s_,       &lds[ss][1][(half) * 8192 + ldsWOff]);              \
        ASYNC16(s_ + 512, &lds[ss][1][(half) * 8192 + ldsWOff + 512]);        \
    } while (0)
#define DSA(ss, ks, fm) (*(const bf16x8*)&lds[ss][0][(ks) * 8192 + aBase + (fm) * 128])
#define DSB(ss, ks, fn) (*(const bf16x8*)&lds[ss][1][(ks) * 8192 + bBase + (fn) * 128])
// 16 MFMA: 4 A-frags (quadrant mh) x 4 B-frags (register-held)
#define CLUSTER(mh, A0_, A1_, A2_, A3_, B0_, B1_, B2_, B3_) do {              \
        __builtin_amdgcn_s_setprio(1);                                        \
        acc[(mh)*4+0][0] = __builtin_amdgcn_mfma_f32_16x16x32_bf16(A0_, B0_, acc[(mh)*4+0][0], 0, 0, 0); \
        acc[(mh)*4+0][1] = __builtin_amdgcn_mfma_f32_16x16x32_bf16(A0_, B1_, acc[(mh)*4+0][1], 0, 0, 0); \
        acc[(mh)*4+0][2] = __builtin_amdgcn_mfma_f32_16x16x32_bf16(A0_, B2_, acc[(mh)*4+0][2], 0, 0, 0); \
        acc[(mh)*4+0][3] = __builtin_amdgcn_mfma_f32_16x16x32_bf16(A0_, B3_, acc[(mh)*4+0][3], 0, 0, 0); \
        acc[(mh)*4+1][0] = __builtin_amdgcn_mfma_f32_16x16x32_bf16(A1_, B0_, acc[(mh)*4+1][0], 0, 0, 0); \
        acc[(mh)*4+1][1] = __builtin_amdgcn_mfma_f32_16x16x32_bf16(A1_, B1_, acc[(mh)*4+1][1], 0, 0, 0); \
        acc[(mh)*4+1][2] = __builtin_amdgcn_mfma_f32_16x16x32_bf16(A1_, B2_, acc[(mh)*4+1][2], 0, 0, 0); \
        acc[(mh)*4+1][3] = __builtin_amdgcn_mfma_f32_16x16x32_bf16(A1_, B3_, acc[(mh)*4+1][3], 0, 0, 0); \
        acc[(mh)*4+2][0] = __builtin_amdgcn_mfma_f32_16x16x32_bf16(A2_, B0_, acc[(mh)*4+2][0], 0, 0, 0); \
        acc[(mh)*4+2][1] = __builtin_amdgcn_mfma_f32_16x16x32_bf16(A2_, B1_, acc[(mh)*4+2][1], 0, 0, 0); \
        acc[(mh)*4+2][2] = __builtin_amdgcn_mfma_f32_16x16x32_bf16(A2_, B2_, acc[(mh)*4+2][2], 0, 0, 0); \
        acc[(mh)*4+2][3] = __builtin_amdgcn_mfma_f32_16x16x32_bf16(A2_, B3_, acc[(mh)*4+2][3], 0, 0, 0); \
        acc[(mh)*4+3][0] = __builtin_amdgcn_mfma_f32_16x16x32_bf16(A3_, B0_, acc[(mh)*4+3][0], 0, 0, 0); \
        acc[(mh)*4+3][1] = __builtin_amdgcn_mfma_f32_16x16x32_bf16(A3_, B1_, acc[(mh)*4+3][1], 0, 0, 0); \
        acc[(mh)*4+3][2] = __builtin_amdgcn_mfma_f32_16x16x32_bf16(A3_, B2_, acc[(mh)*4+3][2], 0, 0, 0); \
        acc[(mh)*4+3][3] = __builtin_amdgcn_mfma_f32_16x16x32_bf16(A3_, B3_, acc[(mh)*4+3][3], 0, 0, 0); \
        __builtin_amdgcn_s_setprio(0);                                        \
    } while (0)

// One K-step: compute set ss (tile staged last step), stage tile tn -> ss^1.
// vmcnt ledger/wave (2 instr per quarter-stage, FIFO): start 8 outstanding
// (all of set ss). +2 (A0') -> 10; vmcnt(2) retires all 8 of ss -> publish
// via barrier. Then clusters run barrier-free: ds_reads of cluster p+1
// overlap cluster p's MFMA. End barrier protects set ss from next staging.
#define KSTEP(ss, tn) do {                                                    \
        STAGE_A(0, tn, (ss)^1);                                               \
        asm volatile("s_waitcnt vmcnt(2)" ::: "memory");                      \
        __builtin_amdgcn_s_barrier();                                         \
        __builtin_amdgcn_sched_barrier(0);                                    \
        bf16x8 a0 = DSA(ss,0,0), a1 = DSA(ss,0,1), a2 = DSA(ss,0,2), a3 = DSA(ss,0,3); \
        bf16x8 b0 = DSB(ss,0,0), b1 = DSB(ss,0,1), b2 = DSB(ss,0,2), b3 = DSB(ss,0,3); \
        STAGE_B(0, tn, (ss)^1);                                               \
        CLUSTER(0, a0, a1, a2, a3, b0, b1, b2, b3);                           \
        bf16x8 a4 = DSA(ss,0,4), a5 = DSA(ss,0,5), a6 = DSA(ss,0,6), a7 = DSA(ss,0,7); \
        STAGE_A(1, tn, (ss)^1);                                               \
        CLUSTER(1, a4, a5, a6, a7, b0, b1, b2, b3);                           \
        bf16x8 c0 = DSA(ss,1,0), c1 = DSA(ss,1,1), c2 = DSA(ss,1,2), c3 = DSA(ss,1,3); \
        bf16x8 d0 = DSB(ss,1,0), d1 = DSB(ss,1,1), d2 = DSB(ss,1,2), d3 = DSB(ss,1,3); \
        STAGE_B(1, tn, (ss)^1);                                               \
        CLUSTER(0, c0, c1, c2, c3, d0, d1, d2, d3);                           \
        bf16x8 c4 = DSA(ss,1,4), c5 = DSA(ss,1,5), c6 = DSA(ss,1,6), c7 = DSA(ss,1,7); \
        CLUSTER(1, c4, c5, c6, c7, d0, d1, d2, d3);                           \
        __builtin_amdgcn_s_barrier();                                         \
        __builtin_amdgcn_sched_barrier(0);                                    \
    } while (0)

    // prologue: tile 0 -> set 0 (outstanding = 8, matches steady state)
    STAGE_A(0, 0, 0);
    STAGE_B(0, 0, 0);
    STAGE_A(1, 0, 0);
    STAGE_B(1, 0, 0);

    for (int t = 0; t < NT; t += 2) {
        const int tn1 = t + 1;                          // <= NT-1
        KSTEP(0, tn1);
        const int tn2 = (t + 2 < NT) ? t + 2 : NT - 1;  // tail: redundant restage
        KSTEP(1, tn2);
    }

    // ---- epilogue: C/D col = lane&15, row = (lane>>4)*4 + r (m89-verified)
    const int crow0 = bm * 256 + wr * 128 + (lane >> 4) * 4;
    const int ccol0 = bn * 256 + wc * 64 + (lane & 15);
#pragma unroll
    for (int fm = 0; fm < 8; ++fm)
#pragma unroll
        for (int fn = 0; fn < 4; ++fn)
#pragma unroll
            for (int r = 0; r < 4; ++r)
                C[(size_t)(crow0 + fm * 16 + r) * N + (ccol0 + fn * 16)] = acc[fm][fn][r];

#undef STAGE_A
#undef STAGE_B
#undef DSA
#undef DSB
#undef CLUSTER
#undef KSTEP
}

// ---------------- fallback: Round-4 fused kernel (proven PASS) ----------------
__device__ inline int lds_off(int row, int slot) {
    return row * 32 + (((slot ^ ((row >> 1) & 3)) & 3) << 3);
}

__global__ __launch_bounds__(256) void gemm_bt_fused(
    const float* __restrict__ A, const float* __restrict__ B,
    float* __restrict__ C, int M, int N, int K)
{
    constexpr int BM = 128, BN = 128, BK = 32;
    __shared__ unsigned short sA[2][BM * BK];
    __shared__ unsigned short sB[2][BN * BK];

    const int nbm = M / BM, nbn = N / BN;
    const int nwg = nbm * nbn;
    const int bid = blockIdx.x;
    int swz = bid;
    if ((nwg & 7) == 0) { const int q = nwg >> 3; swz = (bid & 7) * q + (bid >> 3); }
    const int bm = swz % nbm, bn = swz / nbm;

    const int tid = threadIdx.x;
    const int srow = tid >> 1;
    const int scol = (tid & 1) * 16;
    const float* gA = A + (size_t)(bm * BM + srow) * K + scol;
    const float* gB = B + (size_t)(bn * BN + srow) * K + scol;
    const int s0  = (tid & 1) * 2;
    const int wo0 = lds_off(srow, s0);
    const int wo1 = lds_off(srow, s0 + 1);

    const int wave = tid >> 6, lane = tid & 63;
    const int wr = wave >> 1, wc = wave & 1;
    const int fr = lane & 15;
    const int slr = lane >> 4;
    int offA[4], offB[4];
#pragma unroll
    for (int i = 0; i < 4; ++i) {
        offA[i] = lds_off(wr * 64 + i * 16 + fr, slr);
        offB[i] = lds_off(wc * 64 + i * 16 + fr, slr);
    }

    f32x4 acc[4][4] = {};
    const int NT = K / BK;

    float4 va[4], vb[4];
#pragma unroll
    for (int p = 0; p < 4; ++p) {
        va[p] = *reinterpret_cast<const float4*>(gA + p * 4);
        vb[p] = *reinterpret_cast<const float4*>(gB + p * 4);
    }

    for (int t = 0; t < NT; ++t) {
        const int cur = t & 1;
        u16x8 pa0, pa1, pb0, pb1;
#pragma unroll
        for (int e = 0; e < 4; ++e) {
            pa0[e] = f2bf(va[0][e]);  pa0[4 + e] = f2bf(va[1][e]);
            pa1[e] = f2bf(va[2][e]);  pa1[4 + e] = f2bf(va[3][e]);
            pb0[e] = f2bf(vb[0][e]);  pb0[4 + e] = f2bf(vb[1][e]);
            pb1[e] = f2bf(vb[2][e]);  pb1[4 + e] = f2bf(vb[3][e]);
        }
        *reinterpret_cast<u16x8*>(&sA[cur][wo0]) = pa0;
        *reinterpret_cast<u16x8*>(&sA[cur][wo1]) = pa1;
        *reinterpret_cast<u16x8*>(&sB[cur][wo0]) = pb0;
        *reinterpret_cast<u16x8*>(&sB[cur][wo1]) = pb1;

        const int kn = (t + 1 < NT) ? (t + 1) * BK : t * BK;
#pragma unroll
        for (int p = 0; p < 4; ++p) {
            va[p] = *reinterpret_cast<const float4*>(gA + kn + p * 4);
            vb[p] = *reinterpret_cast<const float4*>(gB + kn + p * 4);
        }

        __syncthreads();

        bf16x8 a[4], b[4];
#pragma unroll
        for (int i = 0; i < 4; ++i) a[i] = *reinterpret_cast<const bf16x8*>(&sA[cur][offA[i]]);
#pragma unroll
        for (int j = 0; j < 4; ++j) b[j] = *reinterpret_cast<const bf16x8*>(&sB[cur][offB[j]]);
#pragma unroll
        for (int i = 0; i < 4; ++i)
#pragma unroll
            for (int j = 0; j < 4; ++j)
                acc[i][j] = __builtin_amdgcn_mfma_f32_16x16x32_bf16(a[i], b[j], acc[i][j], 0, 0, 0);
    }

    const int crow0 = bm * BM + wr * 64 + (lane >> 4) * 4;
    const int ccol0 = bn * BN + wc * 64 + fr;
#pragma unroll
    for (int i = 0; i < 4; ++i)
#pragma unroll
        for (int j = 0; j < 4; ++j)
#pragma unroll
            for (int r = 0; r < 4; ++r)
                C[(size_t)(crow0 + i * 16 + r) * N + (ccol0 + j * 16)] = acc[i][j][r];
}

extern "C" void kernel_launch(void* const* d_in, const int* in_sizes, int n_in,
                              void* d_out, int out_size, void* d_ws, size_t ws_size,
                              hipStream_t stream) {
    int K = 4096;
    int M = in_sizes[0] / K;   // 2048
    int N = in_sizes[1] / K;   // 8192

    const float* x = (const float*)d_in[0];
    const float* w = (const float*)d_in[1];
    float* out     = (float*)d_out;
    unsigned short* wsp = (unsigned short*)d_ws;

    const size_t need = ((size_t)in_sizes[0] + (size_t)in_sizes[1]) * 2;
    const int nwg2 = (M >> 8) * (N >> 8);   // 256

    bool geom_ok = (M % 256 == 0) && (N % 256 == 0) && (K % 128 == 0) &&
                   ((((M >> 8) * (N >> 8)) & 7) == 0);
    int maxB = 0;
    hipError_t oe = hipOccupancyMaxActiveBlocksPerMultiprocessor(&maxB, coop_cvt_gemm3, 512, 0);
    const bool coop_ok = geom_ok && (oe == hipSuccess) && (ws_size >= need) &&
                         ((long long)maxB * 256 >= (long long)nwg2);

    if (coop_ok) {
        void* args[] = {(void*)&x, (void*)&w, (void*)&wsp, (void*)&out,
                        (void*)&M, (void*)&N, (void*)&K};
        hipError_t le = hipLaunchCooperativeKernel(coop_cvt_gemm3, dim3(nwg2), dim3(512),
                                                   args, 0, stream);
        if (le == hipSuccess) return;
    }
    const int nwg = (M / 128) * (N / 128);
    gemm_bt_fused<<<dim3(nwg), dim3(256), 0, stream>>>(x, w, out, M, N, K);
}

// Round 9
// 264.684 us; speedup vs baseline: 1.0034x; 1.0034x over previous
//
#include <hip/hip_runtime.h>
#include <hip/hip_bf16.h>
#include <hip/hip_cooperative_groups.h>
#include <cstdint>

namespace cg = cooperative_groups;

// out[M,N] = x[M,K] @ weight[N,K]^T, fp32 device buffers.
// Cooperative kernel, grid 256 x 512thr, 1 block/CU (128 KB LDS):
//  phase 1: cvt fp32->bf16 into d_ws, TILED+FRAGMENT-ORDERED layout (x4 unroll)
//  grid.sync()
//  phase 2: 256x256 GEMM, BK=64, 8 waves (2x4), m201-faithful 8-phase
//  schedule: per phase {8 ds_read, 2 global_load_lds, s_barrier, lgkmcnt(0)
//  +sched_barrier, setprio(1) 16 MFMA setprio(0), s_barrier}; vmcnt(2) once
//  per K-tile at phase 0 (never 0 in loop). fp32 C.

typedef __bf16 bf16x8 __attribute__((ext_vector_type(8)));
typedef float f32x4 __attribute__((ext_vector_type(4)));
typedef unsigned short u16x8 __attribute__((ext_vector_type(8)));

#define GAS __attribute__((address_space(1)))
#define LAS __attribute__((address_space(3)))
#define ASYNC16(gsrc, ldst)                                                  \
    __builtin_amdgcn_global_load_lds((GAS uint32_t*)(const void*)(gsrc),     \
                                     (LAS uint32_t*)(ldst), 16, 0, 0)

__device__ inline unsigned short f2bf(float f) {
    __hip_bfloat16 h = __float2bfloat16(f);  // RNE
    return *reinterpret_cast<unsigned short*>(&h);
}

__global__ __launch_bounds__(512, 1) void coop_cvt_gemm4(
    const float* __restrict__ A32,       // x      [M,K]
    const float* __restrict__ B32,       // weight [N,K]
    unsigned short* __restrict__ ws,     // bf16 tiled [szX | szW]
    float* __restrict__ C,               // out    [M,N]
    int M, int N, int K)
{
    const int NT  = K >> 6;              // 64 K-tiles
    const int szX = M * K;
    const int szW = N * K;

    // ================= phase 1: cvt fp32 -> tiled bf16 ws =================
    // chunk (16384 shorts) per (tile,kt); within: off = ks*8192 + g*2048 +
    // row*8, where k = kt*64 + ks*32 + g*8.  (layout validated R7/R8)
    {
        const int nA8  = szX >> 3;
        const int tot8 = (szX + szW) >> 3;
        const int S = gridDim.x * blockDim.x;
        int c0 = blockIdx.x * blockDim.x + threadIdx.x;
        for (; c0 + 3 * S < tot8; c0 += 4 * S) {       // 8 loads in flight
            float4 v[8];
#pragma unroll
            for (int u = 0; u < 4; ++u) {
                const int c = c0 + u * S;
                int cl; const float* base;
                if (c < nA8) { cl = c;       base = A32; }
                else         { cl = c - nA8; base = B32; }
                const int cid  = cl >> 11;
                const int c_in = cl & 2047;
                const float* src = base +
                    (size_t)((cid >> 6) * 256 + (c_in & 255)) * K +
                    (cid & 63) * 64 + (c_in >> 10) * 32 + ((c_in >> 8) & 3) * 8;
                v[2 * u]     = *reinterpret_cast<const float4*>(src);
                v[2 * u + 1] = *reinterpret_cast<const float4*>(src + 4);
            }
#pragma unroll
            for (int u = 0; u < 4; ++u) {
                u16x8 o;
                o[0] = f2bf(v[2*u].x);   o[1] = f2bf(v[2*u].y);
                o[2] = f2bf(v[2*u].z);   o[3] = f2bf(v[2*u].w);
                o[4] = f2bf(v[2*u+1].x); o[5] = f2bf(v[2*u+1].y);
                o[6] = f2bf(v[2*u+1].z); o[7] = f2bf(v[2*u+1].w);
                *reinterpret_cast<u16x8*>(ws + ((size_t)(c0 + u * S) << 3)) = o;
            }
        }
        for (; c0 < tot8; c0 += S) {                   // tail (unused at 2048x8192x4096)
            int cl; const float* base;
            if (c0 < nA8) { cl = c0;       base = A32; }
            else          { cl = c0 - nA8; base = B32; }
            const int cid  = cl >> 11;
            const int c_in = cl & 2047;
            const float* src = base +
                (size_t)((cid >> 6) * 256 + (c_in & 255)) * K +
                (cid & 63) * 64 + (c_in >> 10) * 32 + ((c_in >> 8) & 3) * 8;
            float4 v0 = *reinterpret_cast<const float4*>(src);
            float4 v1 = *reinterpret_cast<const float4*>(src + 4);
            u16x8 o;
            o[0] = f2bf(v0.x); o[1] = f2bf(v0.y); o[2] = f2bf(v0.z); o[3] = f2bf(v0.w);
            o[4] = f2bf(v1.x); o[5] = f2bf(v1.y); o[6] = f2bf(v1.z); o[7] = f2bf(v1.w);
            *reinterpret_cast<u16x8*>(ws + ((size_t)c0 << 3)) = o;
        }
    }

    cg::this_grid().sync();
    asm volatile("s_waitcnt vmcnt(0)" ::: "memory");   // clean vmcnt ledger

    // ================= phase 2: GEMM (m201 8-phase port) =================
    __shared__ unsigned short lds[2][2][16384];        // [set][A|B] = 128 KB

    const int nbm = M >> 8;              // 8
    const int nbn = N >> 8;              // 32
    const int bid = blockIdx.x;
    const int swzid = (bid & 7) * ((nbm * nbn) >> 3) + (bid >> 3);
    const int bm = swzid % nbm;          // fast: stream A panels
    const int bn = swzid / nbm;          // slow: B panel L2-resident

    const int tid  = threadIdx.x;
    const int wv   = tid >> 6;
    const int lane = tid & 63;
    const int wr   = wv >> 2;            // 0..1
    const int wc   = wv & 3;             // 0..3

    const unsigned short* wsA = ws + (size_t)(bm * NT) * 16384 + wv * 1024 + lane * 8;
    const unsigned short* wsB = ws + (size_t)szX + (size_t)(bn * NT) * 16384 + wv * 1024 + lane * 8;
    const int ldsWOff = wv * 1024;       // wave-uniform LDS slice

    const int aBase = (lane >> 4) * 2048 + (wr * 128 + (lane & 15)) * 8;
    const int bBase = (lane >> 4) * 2048 + (wc * 64 + (lane & 15)) * 8;

    f32x4 acc[8][4] = {};

// quarter q of tile tt -> set ss: q0=A half0, q1=B half0, q2=A half1, q3=B half1
#define STAGE_Q(q, tt, ss) do {                                               \
        const unsigned short* s_ = (((q) & 1) ? wsB : wsA)                    \
            + (size_t)(tt) * 16384 + ((q) >> 1) * 8192;                       \
        ASYNC16(s_,       &lds[ss][(q) & 1][((q) >> 1) * 8192 + ldsWOff]);    \
        ASYNC16(s_ + 512, &lds[ss][(q) & 1][((q) >> 1) * 8192 + ldsWOff + 512]); \
    } while (0)
#define DSA(ss, ks, fm) (*(const bf16x8*)&lds[ss][0][(ks) * 8192 + aBase + (fm) * 128])
#define DSB(ss, ks, fn) (*(const bf16x8*)&lds[ss][1][(ks) * 8192 + bBase + (fn) * 128])
#define CLUSTER(mh, A0_, A1_, A2_, A3_, B0_, B1_, B2_, B3_) do {              \
        __builtin_amdgcn_s_setprio(1);                                        \
        acc[(mh)*4+0][0] = __builtin_amdgcn_mfma_f32_16x16x32_bf16(A0_, B0_, acc[(mh)*4+0][0], 0, 0, 0); \
        acc[(mh)*4+0][1] = __builtin_amdgcn_mfma_f32_16x16x32_bf16(A0_, B1_, acc[(mh)*4+0][1], 0, 0, 0); \
        acc[(mh)*4+0][2] = __builtin_amdgcn_mfma_f32_16x16x32_bf16(A0_, B2_, acc[(mh)*4+0][2], 0, 0, 0); \
        acc[(mh)*4+0][3] = __builtin_amdgcn_mfma_f32_16x16x32_bf16(A0_, B3_, acc[(mh)*4+0][3], 0, 0, 0); \
        acc[(mh)*4+1][0] = __builtin_amdgcn_mfma_f32_16x16x32_bf16(A1_, B0_, acc[(mh)*4+1][0], 0, 0, 0); \
        acc[(mh)*4+1][1] = __builtin_amdgcn_mfma_f32_16x16x32_bf16(A1_, B1_, acc[(mh)*4+1][1], 0, 0, 0); \
        acc[(mh)*4+1][2] = __builtin_amdgcn_mfma_f32_16x16x32_bf16(A1_, B2_, acc[(mh)*4+1][2], 0, 0, 0); \
        acc[(mh)*4+1][3] = __builtin_amdgcn_mfma_f32_16x16x32_bf16(A1_, B3_, acc[(mh)*4+1][3], 0, 0, 0); \
        acc[(mh)*4+2][0] = __builtin_amdgcn_mfma_f32_16x16x32_bf16(A2_, B0_, acc[(mh)*4+2][0], 0, 0, 0); \
        acc[(mh)*4+2][1] = __builtin_amdgcn_mfma_f32_16x16x32_bf16(A2_, B1_, acc[(mh)*4+2][1], 0, 0, 0); \
        acc[(mh)*4+2][2] = __builtin_amdgcn_mfma_f32_16x16x32_bf16(A2_, B2_, acc[(mh)*4+2][2], 0, 0, 0); \
        acc[(mh)*4+2][3] = __builtin_amdgcn_mfma_f32_16x16x32_bf16(A2_, B3_, acc[(mh)*4+2][3], 0, 0, 0); \
        acc[(mh)*4+3][0] = __builtin_amdgcn_mfma_f32_16x16x32_bf16(A3_, B0_, acc[(mh)*4+3][0], 0, 0, 0); \
        acc[(mh)*4+3][1] = __builtin_amdgcn_mfma_f32_16x16x32_bf16(A3_, B1_, acc[(mh)*4+3][1], 0, 0, 0); \
        acc[(mh)*4+3][2] = __builtin_amdgcn_mfma_f32_16x16x32_bf16(A3_, B2_, acc[(mh)*4+3][2], 0, 0, 0); \
        acc[(mh)*4+3][3] = __builtin_amdgcn_mfma_f32_16x16x32_bf16(A3_, B3_, acc[(mh)*4+3][3], 0, 0, 0); \
        __builtin_amdgcn_s_setprio(0);                                        \
    } while (0)

// Phase 0 (ks=0, mh=0): publish set ss (vmcnt(2) retires its 8 loads, all
// issued last K-tile), THEN read. Ledger: 8 outstanding +2 (q0) -> 10,
// wait 2 => exactly the compute set retired; 2 new stay in flight.
#define PHASE0(ss, tn) do {                                                   \
        STAGE_Q(0, tn, (ss) ^ 1);                                             \
        asm volatile("s_waitcnt vmcnt(2)" ::: "memory");                      \
        __builtin_amdgcn_s_barrier();                                         \
        __builtin_amdgcn_sched_barrier(0);                                    \
        bf16x8 a0 = DSA(ss,0,0), a1 = DSA(ss,0,1), a2 = DSA(ss,0,2), a3 = DSA(ss,0,3); \
        bf16x8 b0 = DSB(ss,0,0), b1 = DSB(ss,0,1), b2 = DSB(ss,0,2), b3 = DSB(ss,0,3); \
        asm volatile("s_waitcnt lgkmcnt(0)" ::: "memory");                    \
        __builtin_amdgcn_sched_barrier(0);                                    \
        CLUSTER(0, a0, a1, a2, a3, b0, b1, b2, b3);                           \
        __builtin_amdgcn_s_barrier();                                         \
    } while (0)
// Phases 1-3: {8 ds_read, 2 gload_lds, barrier, lgkmcnt(0)+fence, MFMA, barrier}.
// Each wave's lgkmcnt(0) precedes its barrier2, so next-phase stage writes
// (issued post-barrier2) cannot race these reads.
#define PHASE_REST(ss, ks, mh, q, tn) do {                                    \
        bf16x8 a0 = DSA(ss,ks,(mh)*4+0), a1 = DSA(ss,ks,(mh)*4+1),            \
               a2 = DSA(ss,ks,(mh)*4+2), a3 = DSA(ss,ks,(mh)*4+3);            \
        bf16x8 b0 = DSB(ss,ks,0), b1 = DSB(ss,ks,1), b2 = DSB(ss,ks,2), b3 = DSB(ss,ks,3); \
        STAGE_Q(q, tn, (ss) ^ 1);                                             \
        __builtin_amdgcn_s_barrier();                                         \
        asm volatile("s_waitcnt lgkmcnt(0)" ::: "memory");                    \
        __builtin_amdgcn_sched_barrier(0);                                    \
        CLUSTER(mh, a0, a1, a2, a3, b0, b1, b2, b3);                          \
        __builtin_amdgcn_s_barrier();                                         \
    } while (0)
#define KTILE(ss, tn) do {                                                    \
        PHASE0(ss, tn);                                                       \
        PHASE_REST(ss, 0, 1, 1, tn);                                          \
        PHASE_REST(ss, 1, 0, 2, tn);                                          \
        PHASE_REST(ss, 1, 1, 3, tn);                                          \
    } while (0)

    // prologue: tile 0 -> set 0 (queue = 8, matches steady state)
    STAGE_Q(0, 0, 0);
    STAGE_Q(1, 0, 0);
    STAGE_Q(2, 0, 0);
    STAGE_Q(3, 0, 0);

    for (int t = 0; t < NT; t += 2) {
        const int tn1 = t + 1;                          // <= NT-1
        KTILE(0, tn1);
        const int tn2 = (t + 2 < NT) ? t + 2 : NT - 1;  // tail: redundant restage
        KTILE(1, tn2);
    }

    // ---- epilogue: C/D col = lane&15, row = (lane>>4)*4 + r (m89-verified)
    const int crow0 = bm * 256 + wr * 128 + (lane >> 4) * 4;
    const int ccol0 = bn * 256 + wc * 64 + (lane & 15);
#pragma unroll
    for (int fm = 0; fm < 8; ++fm)
#pragma unroll
        for (int fn = 0; fn < 4; ++fn)
#pragma unroll
            for (int r = 0; r < 4; ++r)
                C[(size_t)(crow0 + fm * 16 + r) * N + (ccol0 + fn * 16)] = acc[fm][fn][r];

#undef STAGE_Q
#undef DSA
#undef DSB
#undef CLUSTER
#undef PHASE0
#undef PHASE_REST
#undef KTILE
}

// ---------------- fallback: Round-4 fused kernel (proven PASS) ----------------
__device__ inline int lds_off(int row, int slot) {
    return row * 32 + (((slot ^ ((row >> 1) & 3)) & 3) << 3);
}

__global__ __launch_bounds__(256) void gemm_bt_fused(
    const float* __restrict__ A, const float* __restrict__ B,
    float* __restrict__ C, int M, int N, int K)
{
    constexpr int BM = 128, BN = 128, BK = 32;
    __shared__ unsigned short sA[2][BM * BK];
    __shared__ unsigned short sB[2][BN * BK];

    const int nbm = M / BM, nbn = N / BN;
    const int nwg = nbm * nbn;
    const int bid = blockIdx.x;
    int swz = bid;
    if ((nwg & 7) == 0) { const int q = nwg >> 3; swz = (bid & 7) * q + (bid >> 3); }
    const int bm = swz % nbm, bn = swz / nbm;

    const int tid = threadIdx.x;
    const int srow = tid >> 1;
    const int scol = (tid & 1) * 16;
    const float* gA = A + (size_t)(bm * BM + srow) * K + scol;
    const float* gB = B + (size_t)(bn * BN + srow) * K + scol;
    const int s0  = (tid & 1) * 2;
    const int wo0 = lds_off(srow, s0);
    const int wo1 = lds_off(srow, s0 + 1);

    const int wave = tid >> 6, lane = tid & 63;
    const int wr = wave >> 1, wc = wave & 1;
    const int fr = lane & 15;
    const int slr = lane >> 4;
    int offA[4], offB[4];
#pragma unroll
    for (int i = 0; i < 4; ++i) {
        offA[i] = lds_off(wr * 64 + i * 16 + fr, slr);
        offB[i] = lds_off(wc * 64 + i * 16 + fr, slr);
    }

    f32x4 acc[4][4] = {};
    const int NT = K / BK;

    float4 va[4], vb[4];
#pragma unroll
    for (int p = 0; p < 4; ++p) {
        va[p] = *reinterpret_cast<const float4*>(gA + p * 4);
        vb[p] = *reinterpret_cast<const float4*>(gB + p * 4);
    }

    for (int t = 0; t < NT; ++t) {
        const int cur = t & 1;
        u16x8 pa0, pa1, pb0, pb1;
#pragma unroll
        for (int e = 0; e < 4; ++e) {
            pa0[e] = f2bf(va[0][e]);  pa0[4 + e] = f2bf(va[1][e]);
            pa1[e] = f2bf(va[2][e]);  pa1[4 + e] = f2bf(va[3][e]);
            pb0[e] = f2bf(vb[0][e]);  pb0[4 + e] = f2bf(vb[1][e]);
            pb1[e] = f2bf(vb[2][e]);  pb1[4 + e] = f2bf(vb[3][e]);
        }
        *reinterpret_cast<u16x8*>(&sA[cur][wo0]) = pa0;
        *reinterpret_cast<u16x8*>(&sA[cur][wo1]) = pa1;
        *reinterpret_cast<u16x8*>(&sB[cur][wo0]) = pb0;
        *reinterpret_cast<u16x8*>(&sB[cur][wo1]) = pb1;

        const int kn = (t + 1 < NT) ? (t + 1) * BK : t * BK;
#pragma unroll
        for (int p = 0; p < 4; ++p) {
            va[p] = *reinterpret_cast<const float4*>(gA + kn + p * 4);
            vb[p] = *reinterpret_cast<const float4*>(gB + kn + p * 4);
        }

        __syncthreads();

        bf16x8 a[4], b[4];
#pragma unroll
        for (int i = 0; i < 4; ++i) a[i] = *reinterpret_cast<const bf16x8*>(&sA[cur][offA[i]]);
#pragma unroll
        for (int j = 0; j < 4; ++j) b[j] = *reinterpret_cast<const bf16x8*>(&sB[cur][offB[j]]);
#pragma unroll
        for (int i = 0; i < 4; ++i)
#pragma unroll
            for (int j = 0; j < 4; ++j)
                acc[i][j] = __builtin_amdgcn_mfma_f32_16x16x32_bf16(a[i], b[j], acc[i][j], 0, 0, 0);
    }

    const int crow0 = bm * BM + wr * 64 + (lane >> 4) * 4;
    const int ccol0 = bn * BN + wc * 64 + fr;
#pragma unroll
    for (int i = 0; i < 4; ++i)
#pragma unroll
        for (int j = 0; j < 4; ++j)
#pragma unroll
            for (int r = 0; r < 4; ++r)
                C[(size_t)(crow0 + i * 16 + r) * N + (ccol0 + j * 16)] = acc[i][j][r];
}

extern "C" void kernel_launch(void* const* d_in, const int* in_sizes, int n_in,
                              void* d_out, int out_size, void* d_ws, size_t ws_size,
                              hipStream_t stream) {
    int K = 4096;
    int M = in_sizes[0] / K;   // 2048
    int N = in_sizes[1] / K;   // 8192

    const float* x = (const float*)d_in[0];
    const float* w = (const float*)d_in[1];
    float* out     = (float*)d_out;
    unsigned short* wsp = (unsigned short*)d_ws;

    const size_t need = ((size_t)in_sizes[0] + (size_t)in_sizes[1]) * 2;
    const int nwg2 = (M >> 8) * (N >> 8);   // 256

    bool geom_ok = (M % 256 == 0) && (N % 256 == 0) && (K % 128 == 0) &&
                   ((((M >> 8) * (N >> 8)) & 7) == 0);
    int maxB = 0;
    hipError_t oe = hipOccupancyMaxActiveBlocksPerMultiprocessor(&maxB, coop_cvt_gemm4, 512, 0);
    const bool coop_ok = geom_ok && (oe == hipSuccess) && (ws_size >= need) &&
                         ((long long)maxB * 256 >= (long long)nwg2);

    if (coop_ok) {
        void* args[] = {(void*)&x, (void*)&w, (void*)&wsp, (void*)&out,
                        (void*)&M, (void*)&N, (void*)&K};
        hipError_t le = hipLaunchCooperativeKernel(coop_cvt_gemm4, dim3(nwg2), dim3(512),
                                                   args, 0, stream);
        if (le == hipSuccess) return;
    }
    const int nwg = (M / 128) * (N / 128);
    gemm_bt_fused<<<dim3(nwg), dim3(256), 0, stream>>>(x, w, out, M, N, K);
}